// Round 2
// baseline (2315.565 us; speedup 1.0000x reference)
//
#include <hip/hip_runtime.h>

typedef unsigned short u16;
typedef unsigned int u32;
typedef __bf16 bf16x8 __attribute__((ext_vector_type(8)));
typedef float f32x4 __attribute__((ext_vector_type(4)));
typedef unsigned int u32x4 __attribute__((ext_vector_type(4)));

__device__ __forceinline__ float b2f(u16 u) {
    union { float f; u32 i; } c; c.i = ((u32)u) << 16; return c.f;
}
__device__ __forceinline__ u16 f2b(float f) {
    union { float f; u32 i; } c; c.f = f;
    u32 i = c.i;
    u32 r = i + 0x7fffu + ((i >> 16) & 1u);   // RNE
    return (u16)(r >> 16);
}

// ---------------------------------------------------------------------------
// cvt: fp32 -> bf16, 4-wide
// ---------------------------------------------------------------------------
__global__ __launch_bounds__(256) void cvt_f32_bf16(
    const float* __restrict__ in, u16* __restrict__ out, int n4)
{
    int i = blockIdx.x * blockDim.x + threadIdx.x;
    if (i >= n4) return;
    float4 v = ((const float4*)in)[i];
    ushort4 o;
    o.x = f2b(v.x); o.y = f2b(v.y); o.z = f2b(v.z); o.w = f2b(v.w);
    ((ushort4*)out)[i] = o;
}

// ---------------------------------------------------------------------------
// gemm_bt: C[M x N] = A[M x K] @ W[N x K]^T (+ epilogue), bf16 operands, fp32 acc
// 128x128 tile, BK=32, 256 threads (4 waves, 2x2 of 64x64), mfma 16x16x32.
// MODE 0: K1 qkvl GEMM  (W select by col tile; +qkv_b for col<3072) -> bf16 Cb
// MODE 1: diffproj      (C = xorig + gamma*(acc + bias))            -> bf16 Cb
// MODE 2: proj          (C = acc + bias)                            -> fp32 Cf
// ---------------------------------------------------------------------------
template<int MODE>
__global__ __launch_bounds__(256) void gemm_bt(
    const u16* __restrict__ A, int K,
    const u16* __restrict__ W0, const u16* __restrict__ W1,
    const u16* __restrict__ W2, const u16* __restrict__ W3,
    const float* __restrict__ biasp,
    const float* __restrict__ xorig, const float* __restrict__ gammap,
    u16* __restrict__ Cb, float* __restrict__ Cf, int ldc)
{
    // LDS stride 40 elements (80B rows) -> 16B-aligned b128, 2-way bank alias only
    __shared__ u16 As[128 * 40];
    __shared__ u16 Bs[128 * 40];

    const int t    = threadIdx.x;
    const int tm   = blockIdx.x;
    const int tn   = blockIdx.y;
    const int col0 = tn * 128;

    const u16* Wp = W0; int wr0 = col0;
    if (MODE == 0) {
        if (col0 >= 3584)      { Wp = W3; wr0 = col0 - 3584; }
        else if (col0 >= 3328) { Wp = W2; wr0 = col0 - 3328; }
        else if (col0 >= 3072) { Wp = W1; wr0 = col0 - 3072; }
    }

    const int lr = t >> 2;       // 0..63 staging row
    const int cg = t & 3;        // 8-elem col group
    const u32x4* ag0 = (const u32x4*)(A  + (size_t)(tm * 128 +      lr) * K) + cg;
    const u32x4* ag1 = (const u32x4*)(A  + (size_t)(tm * 128 + 64 + lr) * K) + cg;
    const u32x4* bg0 = (const u32x4*)(Wp + (size_t)(wr0       +      lr) * K) + cg;
    const u32x4* bg1 = (const u32x4*)(Wp + (size_t)(wr0       + 64 + lr) * K) + cg;
    u32x4* as0 = (u32x4*)&As[(lr     ) * 40 + cg * 8];
    u32x4* as1 = (u32x4*)&As[(lr + 64) * 40 + cg * 8];
    u32x4* bs0 = (u32x4*)&Bs[(lr     ) * 40 + cg * 8];
    u32x4* bs1 = (u32x4*)&Bs[(lr + 64) * 40 + cg * 8];

    const int wave = t >> 6, lane = t & 63;
    const int wm = (wave >> 1) * 64, wn = (wave & 1) * 64;
    const int fr = lane & 15;     // fragment row (m or n within 16-tile)
    const int fq = lane >> 4;     // quad: k = fq*8..fq*8+7 ; D row = fq*4+reg

    f32x4 acc[4][4];
    #pragma unroll
    for (int i = 0; i < 4; ++i)
        #pragma unroll
        for (int j = 0; j < 4; ++j)
            acc[i][j] = (f32x4){0.f, 0.f, 0.f, 0.f};

    const int kiters = K >> 5;
    for (int kt = 0; kt < kiters; ++kt) {
        u32x4 a0 = ag0[kt * 4], a1 = ag1[kt * 4];
        u32x4 b0 = bg0[kt * 4], b1 = bg1[kt * 4];
        if (kt) __syncthreads();            // WAR: prev tile's frag reads done
        *as0 = a0; *as1 = a1; *bs0 = b0; *bs1 = b1;
        __syncthreads();

        bf16x8 af[4], bfj[4];
        #pragma unroll
        for (int i = 0; i < 4; ++i)
            af[i] = *(const bf16x8*)&As[(wm + i * 16 + fr) * 40 + fq * 8];
        #pragma unroll
        for (int j = 0; j < 4; ++j)
            bfj[j] = *(const bf16x8*)&Bs[(wn + j * 16 + fr) * 40 + fq * 8];
        #pragma unroll
        for (int i = 0; i < 4; ++i)
            #pragma unroll
            for (int j = 0; j < 4; ++j)
                acc[i][j] = __builtin_amdgcn_mfma_f32_16x16x32_bf16(af[i], bfj[j], acc[i][j], 0, 0, 0);
    }

    float gamma = 0.f;
    if (MODE == 1) gamma = *gammap;

    #pragma unroll
    for (int i = 0; i < 4; ++i) {
        const int row0 = tm * 128 + wm + i * 16 + fq * 4;
        #pragma unroll
        for (int j = 0; j < 4; ++j) {
            const int col = col0 + wn + j * 16 + fr;
            #pragma unroll
            for (int r = 0; r < 4; ++r) {
                const int row = row0 + r;
                float val = acc[i][j][r];
                if (MODE == 0) {
                    if (col < 3072) val += biasp[col];
                    Cb[(size_t)row * ldc + col] = f2b(val);
                } else if (MODE == 1) {
                    val = xorig[(size_t)row * 1024 + col] + gamma * (val + biasp[col]);
                    Cb[(size_t)row * ldc + col] = f2b(val);
                } else {
                    val += biasp[col];
                    Cf[(size_t)row * ldc + col] = val;
                }
            }
        }
    }
}

// ---------------------------------------------------------------------------
// attn_k: one block per (window, head). Dual softmax + differential combine.
// qkvl rows (bf16): [q(1024)|k(1024)|v(1024)|ql(256)|kl(256)|vl(256)]
// writes x_orig (fp32) -> d_out scratch, delta_v (bf16) -> ws
// ---------------------------------------------------------------------------
__global__ __launch_bounds__(256) void attn_k(
    const u16* __restrict__ qkvl,
    const float* __restrict__ mask,   // (64,49,49) fp32
    const float* __restrict__ rpb,    // (169,32) fp32
    const int* __restrict__ rpi,      // (49,49) int32
    const float* __restrict__ lam1p, const float* __restrict__ lam2p,
    int win_base,
    float* __restrict__ xorig_out,    // (25088,1024) fp32, global base
    u16* __restrict__ dv_out)         // (25088,256) bf16, global base
{
    const int lb  = blockIdx.x;           // chunk-local window
    const int h   = blockIdx.y;
    const int b   = win_base + lb;        // global window index
    const int win = b & 63;               // mask index (b % 64)

    __shared__ float q[49][32], k[49][32], v[49][32];
    __shared__ float qls[49][8], kls[49][8], vls[49][8];
    __shared__ float S[49][50], Sl[49][50];

    const int t = threadIdx.x;
    const float scale   = 0.17677669529663687f;   // 32^-0.5
    const float scale_l = 0.35355339059327373f;   // 8^-0.5

    for (int idx = t; idx < 1568; idx += 256) {
        int i = idx >> 5, d = idx & 31;
        size_t base = (size_t)(lb * 49 + i) * 3840 + h * 32 + d;
        q[i][d] = b2f(qkvl[base])        * scale;
        k[i][d] = b2f(qkvl[base + 1024]);
        v[i][d] = b2f(qkvl[base + 2048]);
    }
    for (int idx = t; idx < 392; idx += 256) {
        int i = idx >> 3, d = idx & 7;
        size_t base = (size_t)(lb * 49 + i) * 3840 + 3072 + h * 8 + d;
        qls[i][d] = b2f(qkvl[base])       * scale_l;
        kls[i][d] = b2f(qkvl[base + 256]);
        vls[i][d] = b2f(qkvl[base + 512]);
    }
    __syncthreads();

    for (int idx = t; idx < 2401; idx += 256) {
        int i = idx / 49, j = idx - i * 49;
        float bm = rpb[rpi[idx] * 32 + h] + mask[(size_t)win * 2401 + idx];
        float s = 0.f, sl = 0.f;
        #pragma unroll
        for (int d = 0; d < 32; ++d) s += q[i][d] * k[j][d];
        #pragma unroll
        for (int d = 0; d < 8; ++d) sl += qls[i][d] * kls[j][d];
        S[i][j]  = s  + bm;
        Sl[i][j] = sl + bm;
    }
    __syncthreads();

    const float lam1 = 1.f / (1.f + __expf(-*lam1p));
    const float lam2 = 1.f / (1.f + __expf(-*lam2p));

    const int wave = t >> 6, j = t & 63;
    const bool jb = (j < 49);
    for (int i = wave; i < 49; i += 4) {
        float s = jb ? S[i][j] : -1e30f;
        float m = s;
        #pragma unroll
        for (int off = 32; off > 0; off >>= 1) m = fmaxf(m, __shfl_xor(m, off));
        float e = jb ? __expf(s - m) : 0.f;
        float sum = e;
        #pragma unroll
        for (int off = 32; off > 0; off >>= 1) sum += __shfl_xor(sum, off);
        float p = e / sum;

        float s2 = jb ? Sl[i][j] : -1e30f;
        float m2 = s2;
        #pragma unroll
        for (int off = 32; off > 0; off >>= 1) m2 = fmaxf(m2, __shfl_xor(m2, off));
        float e2 = jb ? __expf(s2 - m2) : 0.f;
        float sum2 = e2;
        #pragma unroll
        for (int off = 32; off > 0; off >>= 1) sum2 += __shfl_xor(sum2, off);
        float pl = e2 / sum2;

        if (jb) {
            S[i][j]  = p;                    // attn_sm
            Sl[i][j] = lam1 * pl - lam2 * p; // diff
        }
    }
    __syncthreads();

    for (int idx = t; idx < 1568; idx += 256) {
        int i = idx >> 5, d = idx & 31;
        float acc = 0.f;
        #pragma unroll 7
        for (int jj = 0; jj < 49; ++jj) acc += S[i][jj] * v[jj][d];
        xorig_out[(size_t)(b * 49 + i) * 1024 + h * 32 + d] = acc;
    }
    for (int idx = t; idx < 392; idx += 256) {
        int i = idx >> 3, d = idx & 7;
        float acc = 0.f;
        #pragma unroll 7
        for (int jj = 0; jj < 49; ++jj) acc += Sl[i][jj] * vls[jj][d];
        dv_out[(size_t)(b * 49 + i) * 256 + h * 8 + d] = f2b(acc);
    }
}

// ---------------------------------------------------------------------------
extern "C" void kernel_launch(void* const* d_in, const int* in_sizes, int n_in,
                              void* d_out, int out_size, void* d_ws, size_t ws_size,
                              hipStream_t stream)
{
    const float* x      = (const float*)d_in[0];
    const float* mask   = (const float*)d_in[1];
    const float* qkv_w  = (const float*)d_in[2];
    const float* qkv_b  = (const float*)d_in[3];
    const float* proj_w = (const float*)d_in[4];
    const float* proj_b = (const float*)d_in[5];
    const float* rpb    = (const float*)d_in[6];
    const float* ql_w   = (const float*)d_in[7];
    const float* kl_w   = (const float*)d_in[8];
    const float* vl_w   = (const float*)d_in[9];
    const float* lam1   = (const float*)d_in[10];
    const float* lam2   = (const float*)d_in[11];
    const float* dp_w   = (const float*)d_in[12];
    const float* dp_b   = (const float*)d_in[13];
    const float* gamma  = (const float*)d_in[14];
    const int*   rpi    = (const int*)d_in[15];
    float* out = (float*)d_out;

    // chunk count over windows (graph-safe: depends only on ws_size)
    // need(nc) = dv(12.85M) + wbuf(10.49M) + xbuf(mc*2KB) + regA(mc*7.5KB)
    int nc;
    if      (ws_size >= 267386880ull) nc = 1;
    else if (ws_size >= 145358848ull) nc = 2;
    else                              nc = 4;   // needs 84,344,832 B
    const int wpc = 512 / nc;        // windows per chunk
    const int mc  = 25088 / nc;      // token rows per chunk (multiple of 128)

    // ws layout (bf16 elements)
    u16* dv   = (u16*)d_ws;                 // 25088*256
    u16* wbuf = dv + 6422528;               // 5,242,880 elements
    u16* xbuf = wbuf + 5242880;             // mc*1024
    u16* regA = xbuf + (size_t)mc * 1024;   // mc*3840 (phase1) / mc*1024 (phase2)

    u16* w_qkv = wbuf;
    u16* w_ql  = wbuf + 3145728;
    u16* w_kl  = wbuf + 3407872;
    u16* w_vl  = wbuf + 3670016;
    u16* w_dp  = wbuf + 3932160;
    u16* w_pj  = wbuf + 4194304;

    // convert weights to bf16 (once per call)
    cvt_f32_bf16<<<3072, 256, 0, stream>>>(qkv_w,  w_qkv, 786432);
    cvt_f32_bf16<<< 256, 256, 0, stream>>>(ql_w,   w_ql,   65536);
    cvt_f32_bf16<<< 256, 256, 0, stream>>>(kl_w,   w_kl,   65536);
    cvt_f32_bf16<<< 256, 256, 0, stream>>>(vl_w,   w_vl,   65536);
    cvt_f32_bf16<<< 256, 256, 0, stream>>>(dp_w,   w_dp,   65536);
    cvt_f32_bf16<<<1024, 256, 0, stream>>>(proj_w, w_pj,  262144);

    // Phase 1: per chunk: cvt x -> qkvl GEMM -> attention
    for (int c = 0; c < nc; ++c) {
        const float* xc = x + (size_t)c * mc * 1024;
        cvt_f32_bf16<<<mc, 256, 0, stream>>>(xc, xbuf, mc * 256);
        gemm_bt<0><<<dim3(mc / 128, 30), 256, 0, stream>>>(
            xbuf, 1024, w_qkv, w_ql, w_kl, w_vl, qkv_b,
            nullptr, nullptr, regA, nullptr, 3840);
        attn_k<<<dim3(wpc, 32), 256, 0, stream>>>(
            regA, mask, rpb, rpi, lam1, lam2, c * wpc, out, dv);
    }
    // Phase 2: per chunk: diffproj (+residual from out scratch) -> final proj
    for (int c = 0; c < nc; ++c) {
        size_t r0 = (size_t)c * mc;
        gemm_bt<1><<<dim3(mc / 128, 8), 256, 0, stream>>>(
            dv + r0 * 256, 256, w_dp, nullptr, nullptr, nullptr, dp_b,
            out + r0 * 1024, gamma, regA, nullptr, 1024);
        gemm_bt<2><<<dim3(mc / 128, 8), 256, 0, stream>>>(
            regA, 1024, w_pj, nullptr, nullptr, nullptr, proj_b,
            nullptr, nullptr, nullptr, out + r0 * 1024, 1024);
    }
}

// Round 3
// 1435.019 us; speedup vs baseline: 1.6136x; 1.6136x over previous
//
#include <hip/hip_runtime.h>

typedef unsigned short u16;
typedef unsigned int u32;
typedef __bf16 bf16x8 __attribute__((ext_vector_type(8)));
typedef float f32x4 __attribute__((ext_vector_type(4)));
typedef unsigned int u32x4 __attribute__((ext_vector_type(4)));

__device__ __forceinline__ float b2f(u16 u) {
    union { float f; u32 i; } c; c.i = ((u32)u) << 16; return c.f;
}
__device__ __forceinline__ u16 f2b(float f) {
    union { float f; u32 i; } c; c.f = f;
    u32 i = c.i;
    u32 r = i + 0x7fffu + ((i >> 16) & 1u);   // RNE
    return (u16)(r >> 16);
}

// ---------------------------------------------------------------------------
// cvt: fp32 -> bf16, 4-wide
// ---------------------------------------------------------------------------
__global__ __launch_bounds__(256) void cvt_f32_bf16(
    const float* __restrict__ in, u16* __restrict__ out, int n4)
{
    int i = blockIdx.x * blockDim.x + threadIdx.x;
    if (i >= n4) return;
    float4 v = ((const float4*)in)[i];
    ushort4 o;
    o.x = f2b(v.x); o.y = f2b(v.y); o.z = f2b(v.z); o.w = f2b(v.w);
    ((ushort4*)out)[i] = o;
}

// ---------------------------------------------------------------------------
// gemm_bt: C[M x N] = A[M x K] @ W[N x K]^T (+ epilogue), bf16 operands, fp32 acc
// 128x128 tile, BK=32, 256 threads (4 waves, 2x2 of 64x64), mfma 16x16x32.
// MODE 0: K1 qkvl GEMM  (W select by col tile; +qkv_b for col<3072) -> bf16 Cb
// MODE 1: diffproj      (C = xorig + gamma*(acc + bias))            -> bf16 Cb
// MODE 2: proj          (C = acc + bias)                            -> fp32 Cf
// ---------------------------------------------------------------------------
template<int MODE>
__global__ __launch_bounds__(256) void gemm_bt(
    const u16* __restrict__ A, int K,
    const u16* __restrict__ W0, const u16* __restrict__ W1,
    const u16* __restrict__ W2, const u16* __restrict__ W3,
    const float* __restrict__ biasp,
    const float* __restrict__ xorig, const float* __restrict__ gammap,
    u16* __restrict__ Cb, float* __restrict__ Cf, int ldc)
{
    // LDS stride 40 elements (80B rows) -> 16B-aligned b128, 2-way bank alias only
    __shared__ u16 As[128 * 40];
    __shared__ u16 Bs[128 * 40];

    const int t    = threadIdx.x;
    const int tm   = blockIdx.x;
    const int tn   = blockIdx.y;
    const int col0 = tn * 128;

    const u16* Wp = W0; int wr0 = col0;
    if (MODE == 0) {
        if (col0 >= 3584)      { Wp = W3; wr0 = col0 - 3584; }
        else if (col0 >= 3328) { Wp = W2; wr0 = col0 - 3328; }
        else if (col0 >= 3072) { Wp = W1; wr0 = col0 - 3072; }
    }

    const int lr = t >> 2;       // 0..63 staging row
    const int cg = t & 3;        // 8-elem col group
    const u32x4* ag0 = (const u32x4*)(A  + (size_t)(tm * 128 +      lr) * K) + cg;
    const u32x4* ag1 = (const u32x4*)(A  + (size_t)(tm * 128 + 64 + lr) * K) + cg;
    const u32x4* bg0 = (const u32x4*)(Wp + (size_t)(wr0       +      lr) * K) + cg;
    const u32x4* bg1 = (const u32x4*)(Wp + (size_t)(wr0       + 64 + lr) * K) + cg;
    u32x4* as0 = (u32x4*)&As[(lr     ) * 40 + cg * 8];
    u32x4* as1 = (u32x4*)&As[(lr + 64) * 40 + cg * 8];
    u32x4* bs0 = (u32x4*)&Bs[(lr     ) * 40 + cg * 8];
    u32x4* bs1 = (u32x4*)&Bs[(lr + 64) * 40 + cg * 8];

    const int wave = t >> 6, lane = t & 63;
    const int wm = (wave >> 1) * 64, wn = (wave & 1) * 64;
    const int fr = lane & 15;     // fragment row (m or n within 16-tile)
    const int fq = lane >> 4;     // quad: k = fq*8..fq*8+7 ; D row = fq*4+reg

    f32x4 acc[4][4];
    #pragma unroll
    for (int i = 0; i < 4; ++i)
        #pragma unroll
        for (int j = 0; j < 4; ++j)
            acc[i][j] = (f32x4){0.f, 0.f, 0.f, 0.f};

    const int kiters = K >> 5;
    for (int kt = 0; kt < kiters; ++kt) {
        u32x4 a0 = ag0[kt * 4], a1 = ag1[kt * 4];
        u32x4 b0 = bg0[kt * 4], b1 = bg1[kt * 4];
        if (kt) __syncthreads();            // WAR: prev tile's frag reads done
        *as0 = a0; *as1 = a1; *bs0 = b0; *bs1 = b1;
        __syncthreads();

        bf16x8 af[4], bfj[4];
        #pragma unroll
        for (int i = 0; i < 4; ++i)
            af[i] = *(const bf16x8*)&As[(wm + i * 16 + fr) * 40 + fq * 8];
        #pragma unroll
        for (int j = 0; j < 4; ++j)
            bfj[j] = *(const bf16x8*)&Bs[(wn + j * 16 + fr) * 40 + fq * 8];
        #pragma unroll
        for (int i = 0; i < 4; ++i)
            #pragma unroll
            for (int j = 0; j < 4; ++j)
                acc[i][j] = __builtin_amdgcn_mfma_f32_16x16x32_bf16(af[i], bfj[j], acc[i][j], 0, 0, 0);
    }

    float gamma = 0.f;
    if (MODE == 1) gamma = *gammap;

    #pragma unroll
    for (int i = 0; i < 4; ++i) {
        const int row0 = tm * 128 + wm + i * 16 + fq * 4;
        #pragma unroll
        for (int j = 0; j < 4; ++j) {
            const int col = col0 + wn + j * 16 + fr;
            #pragma unroll
            for (int r = 0; r < 4; ++r) {
                const int row = row0 + r;
                float val = acc[i][j][r];
                if (MODE == 0) {
                    if (col < 3072) val += biasp[col];
                    Cb[(size_t)row * ldc + col] = f2b(val);
                } else if (MODE == 1) {
                    val = xorig[(size_t)row * 1024 + col] + gamma * (val + biasp[col]);
                    Cb[(size_t)row * ldc + col] = f2b(val);
                } else {
                    val += biasp[col];
                    Cf[(size_t)row * ldc + col] = val;
                }
            }
        }
    }
}

// ---------------------------------------------------------------------------
// attn_k: one block per (window, head). Dual softmax + differential combine.
// qkvl rows (bf16): [q(1024)|k(1024)|v(1024)|ql(256)|kl(256)|vl(256)]
// writes x_orig (fp32) -> d_out scratch, delta_v (bf16) -> ws
// LDS leading dims padded (33 / 9) so j-varying accesses are bank-spread:
//   (33*j+d)%32 = (j+d)%32 -> 2-way alias max (free); 9j%32 distinct (gcd=1).
// ---------------------------------------------------------------------------
__global__ __launch_bounds__(256) void attn_k(
    const u16* __restrict__ qkvl,
    const float* __restrict__ mask,   // (64,49,49) fp32
    const float* __restrict__ rpb,    // (169,32) fp32
    const int* __restrict__ rpi,      // (49,49) int32
    const float* __restrict__ lam1p, const float* __restrict__ lam2p,
    int win_base,
    float* __restrict__ xorig_out,    // (25088,1024) fp32, global base
    u16* __restrict__ dv_out)         // (25088,256) bf16, global base
{
    const int lb  = blockIdx.x;           // chunk-local window
    const int h   = blockIdx.y;
    const int b   = win_base + lb;        // global window index
    const int win = b & 63;               // mask index (b % 64)

    __shared__ float q[49][33], k[49][33], v[49][33];
    __shared__ float qls[49][9], kls[49][9], vls[49][9];
    __shared__ float S[49][50], Sl[49][50];

    const int t = threadIdx.x;
    const float scale   = 0.17677669529663687f;   // 32^-0.5
    const float scale_l = 0.35355339059327373f;   // 8^-0.5

    for (int idx = t; idx < 1568; idx += 256) {
        int i = idx >> 5, d = idx & 31;
        size_t base = (size_t)(lb * 49 + i) * 3840 + h * 32 + d;
        q[i][d] = b2f(qkvl[base])        * scale;
        k[i][d] = b2f(qkvl[base + 1024]);
        v[i][d] = b2f(qkvl[base + 2048]);
    }
    for (int idx = t; idx < 392; idx += 256) {
        int i = idx >> 3, d = idx & 7;
        size_t base = (size_t)(lb * 49 + i) * 3840 + 3072 + h * 8 + d;
        qls[i][d] = b2f(qkvl[base])       * scale_l;
        kls[i][d] = b2f(qkvl[base + 256]);
        vls[i][d] = b2f(qkvl[base + 512]);
    }
    __syncthreads();

    for (int idx = t; idx < 2401; idx += 256) {
        int i = idx / 49, j = idx - i * 49;
        float bm = rpb[rpi[idx] * 32 + h] + mask[(size_t)win * 2401 + idx];
        float s = 0.f, sl = 0.f;
        #pragma unroll
        for (int d = 0; d < 32; ++d) s += q[i][d] * k[j][d];
        #pragma unroll
        for (int d = 0; d < 8; ++d) sl += qls[i][d] * kls[j][d];
        S[i][j]  = s  + bm;
        Sl[i][j] = sl + bm;
    }
    __syncthreads();

    const float lam1 = 1.f / (1.f + __expf(-*lam1p));
    const float lam2 = 1.f / (1.f + __expf(-*lam2p));

    const int wave = t >> 6, j = t & 63;
    const bool jb = (j < 49);
    for (int i = wave; i < 49; i += 4) {
        float s = jb ? S[i][j] : -1e30f;
        float m = s;
        #pragma unroll
        for (int off = 32; off > 0; off >>= 1) m = fmaxf(m, __shfl_xor(m, off));
        float e = jb ? __expf(s - m) : 0.f;
        float sum = e;
        #pragma unroll
        for (int off = 32; off > 0; off >>= 1) sum += __shfl_xor(sum, off);
        float p = e / sum;

        float s2 = jb ? Sl[i][j] : -1e30f;
        float m2 = s2;
        #pragma unroll
        for (int off = 32; off > 0; off >>= 1) m2 = fmaxf(m2, __shfl_xor(m2, off));
        float e2 = jb ? __expf(s2 - m2) : 0.f;
        float sum2 = e2;
        #pragma unroll
        for (int off = 32; off > 0; off >>= 1) sum2 += __shfl_xor(sum2, off);
        float pl = e2 / sum2;

        if (jb) {
            S[i][j]  = p;                    // attn_sm
            Sl[i][j] = lam1 * pl - lam2 * p; // diff
        }
    }
    __syncthreads();

    for (int idx = t; idx < 1568; idx += 256) {
        int i = idx >> 5, d = idx & 31;
        float acc = 0.f;
        #pragma unroll 7
        for (int jj = 0; jj < 49; ++jj) acc += S[i][jj] * v[jj][d];
        xorig_out[(size_t)(b * 49 + i) * 1024 + h * 32 + d] = acc;
    }
    for (int idx = t; idx < 392; idx += 256) {
        int i = idx >> 3, d = idx & 7;
        float acc = 0.f;
        #pragma unroll 7
        for (int jj = 0; jj < 49; ++jj) acc += Sl[i][jj] * vls[jj][d];
        dv_out[(size_t)(b * 49 + i) * 256 + h * 8 + d] = f2b(acc);
    }
}

// ---------------------------------------------------------------------------
extern "C" void kernel_launch(void* const* d_in, const int* in_sizes, int n_in,
                              void* d_out, int out_size, void* d_ws, size_t ws_size,
                              hipStream_t stream)
{
    const float* x      = (const float*)d_in[0];
    const float* mask   = (const float*)d_in[1];
    const float* qkv_w  = (const float*)d_in[2];
    const float* qkv_b  = (const float*)d_in[3];
    const float* proj_w = (const float*)d_in[4];
    const float* proj_b = (const float*)d_in[5];
    const float* rpb    = (const float*)d_in[6];
    const float* ql_w   = (const float*)d_in[7];
    const float* kl_w   = (const float*)d_in[8];
    const float* vl_w   = (const float*)d_in[9];
    const float* lam1   = (const float*)d_in[10];
    const float* lam2   = (const float*)d_in[11];
    const float* dp_w   = (const float*)d_in[12];
    const float* dp_b   = (const float*)d_in[13];
    const float* gamma  = (const float*)d_in[14];
    const int*   rpi    = (const int*)d_in[15];
    float* out = (float*)d_out;

    // chunk count over windows (graph-safe: depends only on ws_size)
    int nc;
    if      (ws_size >= 267386880ull) nc = 1;
    else if (ws_size >= 145358848ull) nc = 2;
    else                              nc = 4;   // needs 84,344,832 B
    const int wpc = 512 / nc;        // windows per chunk
    const int mc  = 25088 / nc;      // token rows per chunk (multiple of 128)

    // ws layout (bf16 elements)
    u16* dv   = (u16*)d_ws;                 // 25088*256
    u16* wbuf = dv + 6422528;               // 5,242,880 elements
    u16* xbuf = wbuf + 5242880;             // mc*1024
    u16* regA = xbuf + (size_t)mc * 1024;   // mc*3840 (phase1) / mc*1024 (phase2)

    u16* w_qkv = wbuf;
    u16* w_ql  = wbuf + 3145728;
    u16* w_kl  = wbuf + 3407872;
    u16* w_vl  = wbuf + 3670016;
    u16* w_dp  = wbuf + 3932160;
    u16* w_pj  = wbuf + 4194304;

    // convert weights to bf16 (once per call)
    cvt_f32_bf16<<<3072, 256, 0, stream>>>(qkv_w,  w_qkv, 786432);
    cvt_f32_bf16<<< 256, 256, 0, stream>>>(ql_w,   w_ql,   65536);
    cvt_f32_bf16<<< 256, 256, 0, stream>>>(kl_w,   w_kl,   65536);
    cvt_f32_bf16<<< 256, 256, 0, stream>>>(vl_w,   w_vl,   65536);
    cvt_f32_bf16<<< 256, 256, 0, stream>>>(dp_w,   w_dp,   65536);
    cvt_f32_bf16<<<1024, 256, 0, stream>>>(proj_w, w_pj,  262144);

    // Phase 1: per chunk: cvt x -> qkvl GEMM -> attention
    for (int c = 0; c < nc; ++c) {
        const float* xc = x + (size_t)c * mc * 1024;
        cvt_f32_bf16<<<mc, 256, 0, stream>>>(xc, xbuf, mc * 256);
        gemm_bt<0><<<dim3(mc / 128, 30), 256, 0, stream>>>(
            xbuf, 1024, w_qkv, w_ql, w_kl, w_vl, qkv_b,
            nullptr, nullptr, regA, nullptr, 3840);
        attn_k<<<dim3(wpc, 32), 256, 0, stream>>>(
            regA, mask, rpb, rpi, lam1, lam2, c * wpc, out, dv);
    }
    // Phase 2: per chunk: diffproj (+residual from out scratch) -> final proj
    for (int c = 0; c < nc; ++c) {
        size_t r0 = (size_t)c * mc;
        gemm_bt<1><<<dim3(mc / 128, 8), 256, 0, stream>>>(
            dv + r0 * 256, 256, w_dp, nullptr, nullptr, nullptr, dp_b,
            out + r0 * 1024, gamma, regA, nullptr, 1024);
        gemm_bt<2><<<dim3(mc / 128, 8), 256, 0, stream>>>(
            regA, 1024, w_pj, nullptr, nullptr, nullptr, proj_b,
            nullptr, nullptr, nullptr, out + r0 * 1024, 1024);
    }
}

// Round 4
// 938.253 us; speedup vs baseline: 2.4680x; 1.5295x over previous
//
#include <hip/hip_runtime.h>

typedef unsigned short u16;
typedef unsigned int u32;
typedef __bf16 bf16x8 __attribute__((ext_vector_type(8)));
typedef float f32x4 __attribute__((ext_vector_type(4)));
typedef unsigned int u32x4 __attribute__((ext_vector_type(4)));

__device__ __forceinline__ float b2f(u16 u) {
    union { float f; u32 i; } c; c.i = ((u32)u) << 16; return c.f;
}
__device__ __forceinline__ u16 f2b(float f) {
    union { float f; u32 i; } c; c.f = f;
    u32 i = c.i;
    u32 r = i + 0x7fffu + ((i >> 16) & 1u);   // RNE
    return (u16)(r >> 16);
}

union FU8 { u32x4 u; bf16x8 v; };
__device__ __forceinline__ bf16x8 zero8() { FU8 z; z.u = (u32x4){0,0,0,0}; return z.v; }

// ---------------------------------------------------------------------------
// cvt: fp32 -> bf16, 4-wide
// ---------------------------------------------------------------------------
__global__ __launch_bounds__(256) void cvt_f32_bf16(
    const float* __restrict__ in, u16* __restrict__ out, int n4)
{
    int i = blockIdx.x * blockDim.x + threadIdx.x;
    if (i >= n4) return;
    float4 v = ((const float4*)in)[i];
    ushort4 o;
    o.x = f2b(v.x); o.y = f2b(v.y); o.z = f2b(v.z); o.w = f2b(v.w);
    ((ushort4*)out)[i] = o;
}

// ---------------------------------------------------------------------------
// gemm_bt: C[M x N] = A[M x K] @ W[N x K]^T (+ epilogue), bf16 operands, fp32 acc
// (unchanged from round 3 — 128x128 tile, BK=32, mfma 16x16x32)
// ---------------------------------------------------------------------------
template<int MODE>
__global__ __launch_bounds__(256) void gemm_bt(
    const u16* __restrict__ A, int K,
    const u16* __restrict__ W0, const u16* __restrict__ W1,
    const u16* __restrict__ W2, const u16* __restrict__ W3,
    const float* __restrict__ biasp,
    const float* __restrict__ xorig, const float* __restrict__ gammap,
    u16* __restrict__ Cb, float* __restrict__ Cf, int ldc)
{
    __shared__ u16 As[128 * 40];
    __shared__ u16 Bs[128 * 40];

    const int t    = threadIdx.x;
    const int tm   = blockIdx.x;
    const int tn   = blockIdx.y;
    const int col0 = tn * 128;

    const u16* Wp = W0; int wr0 = col0;
    if (MODE == 0) {
        if (col0 >= 3584)      { Wp = W3; wr0 = col0 - 3584; }
        else if (col0 >= 3328) { Wp = W2; wr0 = col0 - 3328; }
        else if (col0 >= 3072) { Wp = W1; wr0 = col0 - 3072; }
    }

    const int lr = t >> 2;
    const int cg = t & 3;
    const u32x4* ag0 = (const u32x4*)(A  + (size_t)(tm * 128 +      lr) * K) + cg;
    const u32x4* ag1 = (const u32x4*)(A  + (size_t)(tm * 128 + 64 + lr) * K) + cg;
    const u32x4* bg0 = (const u32x4*)(Wp + (size_t)(wr0       +      lr) * K) + cg;
    const u32x4* bg1 = (const u32x4*)(Wp + (size_t)(wr0       + 64 + lr) * K) + cg;
    u32x4* as0 = (u32x4*)&As[(lr     ) * 40 + cg * 8];
    u32x4* as1 = (u32x4*)&As[(lr + 64) * 40 + cg * 8];
    u32x4* bs0 = (u32x4*)&Bs[(lr     ) * 40 + cg * 8];
    u32x4* bs1 = (u32x4*)&Bs[(lr + 64) * 40 + cg * 8];

    const int wave = t >> 6, lane = t & 63;
    const int wm = (wave >> 1) * 64, wn = (wave & 1) * 64;
    const int fr = lane & 15;
    const int fq = lane >> 4;

    f32x4 acc[4][4];
    #pragma unroll
    for (int i = 0; i < 4; ++i)
        #pragma unroll
        for (int j = 0; j < 4; ++j)
            acc[i][j] = (f32x4){0.f, 0.f, 0.f, 0.f};

    const int kiters = K >> 5;
    for (int kt = 0; kt < kiters; ++kt) {
        u32x4 a0 = ag0[kt * 4], a1 = ag1[kt * 4];
        u32x4 b0 = bg0[kt * 4], b1 = bg1[kt * 4];
        if (kt) __syncthreads();
        *as0 = a0; *as1 = a1; *bs0 = b0; *bs1 = b1;
        __syncthreads();

        bf16x8 af[4], bfj[4];
        #pragma unroll
        for (int i = 0; i < 4; ++i)
            af[i] = *(const bf16x8*)&As[(wm + i * 16 + fr) * 40 + fq * 8];
        #pragma unroll
        for (int j = 0; j < 4; ++j)
            bfj[j] = *(const bf16x8*)&Bs[(wn + j * 16 + fr) * 40 + fq * 8];
        #pragma unroll
        for (int i = 0; i < 4; ++i)
            #pragma unroll
            for (int j = 0; j < 4; ++j)
                acc[i][j] = __builtin_amdgcn_mfma_f32_16x16x32_bf16(af[i], bfj[j], acc[i][j], 0, 0, 0);
    }

    float gamma = 0.f;
    if (MODE == 1) gamma = *gammap;

    #pragma unroll
    for (int i = 0; i < 4; ++i) {
        const int row0 = tm * 128 + wm + i * 16 + fq * 4;
        #pragma unroll
        for (int j = 0; j < 4; ++j) {
            const int col = col0 + wn + j * 16 + fr;
            #pragma unroll
            for (int r = 0; r < 4; ++r) {
                const int row = row0 + r;
                float val = acc[i][j][r];
                if (MODE == 0) {
                    if (col < 3072) val += biasp[col];
                    Cb[(size_t)row * ldc + col] = f2b(val);
                } else if (MODE == 1) {
                    val = xorig[(size_t)row * 1024 + col] + gamma * (val + biasp[col]);
                    Cb[(size_t)row * ldc + col] = f2b(val);
                } else {
                    val += biasp[col];
                    Cf[(size_t)row * ldc + col] = val;
                }
            }
        }
    }
}

// ---------------------------------------------------------------------------
// attn_mfma: block = 4 waves = 4 heads of one window. Grid (windows, 8).
// Per wave: S^T = K·Q via MFMA (row=j, col=i), in-register dual softmax,
// P round-trip through wave-private LDS (b64 writes / b128 A-frag reads),
// PV + PVlite via MFMA with V/Vl staged transposed.
// Verified layouts (m89/m91): A/B frag: idx=lane&15, k=(lane>>4)*8+j;
// D: row = first-operand idx = (lane>>4)*4+reg, col = second-operand idx = lane&15.
// ---------------------------------------------------------------------------
__global__ __launch_bounds__(256) void attn_mfma(
    const u16* __restrict__ qkvl,     // [chunk rows][3840] bf16
    const float* __restrict__ mask,   // (64,49,49) fp32
    const float* __restrict__ rpb,    // (169,32) fp32
    const int* __restrict__ rpi,      // (49,49) int32
    const float* __restrict__ lam1p, const float* __restrict__ lam2p,
    int win_base,
    float* __restrict__ xorig_out,    // (25088,1024) fp32, global base
    u16* __restrict__ dv_out)         // (25088,256) bf16, global base
{
    // LDS layout (bytes):
    //  per-wave (w*12816): P[49][72] u16 (7056) | VT[32][72] u16 (4608) | VlT[8][72] u16 (1152)
    //  shared: maskb u16[2401] @51264 | rpi16 u16[2401] @56068 | rpbl f32[4*169] @60872
    __shared__ __align__(16) char lds[63584];

    const int t  = threadIdx.x;
    const int w  = t >> 6, lane = t & 63;
    const int fr = lane & 15, fq = lane >> 4;
    const int lb = blockIdx.x;
    const int hg = blockIdx.y;
    const int h  = hg * 4 + w;
    const int b  = win_base + lb;
    const int win = b & 63;

    u16* P     = (u16*)(lds + w * 12816);
    u16* VT    = (u16*)(lds + w * 12816 + 7056);
    u16* VlT   = (u16*)(lds + w * 12816 + 11664);
    u16* maskb = (u16*)(lds + 51264);
    u16* rpi16 = (u16*)(lds + 56068);
    float* rpbl = (float*)(lds + 60872);

    // ---- block-shared staging ----
    for (int idx = t; idx < 2401; idx += 256) {
        maskb[idx] = f2b(mask[(size_t)win * 2401 + idx]);
        rpi16[idx] = (u16)rpi[idx];
    }
    for (int idx = t; idx < 676; idx += 256) {
        int hl = idx / 169, rid = idx - hl * 169;
        rpbl[idx] = rpb[rid * 32 + hg * 4 + hl];
    }

    // ---- wave-private V / Vl transpose staging (bf16 copy, j-contiguous) ----
    const size_t rowb = (size_t)lb * 49;
    {
        int jr = lane < 49 ? lane : 48;
        const u16* vcol = qkvl + (rowb + jr) * 3840 + 2048 + h * 32;
        #pragma unroll 4
        for (int d = 0; d < 32; ++d)
            VT[d * 72 + lane] = vcol[d];
        const u16* vlcol = qkvl + (rowb + jr) * 3840 + 3584 + h * 8;
        #pragma unroll
        for (int d = 0; d < 8; ++d)
            VlT[d * 72 + lane] = vlcol[d];
    }

    // ---- Q/K fragment loads straight from global (16B each, row-clamped) ----
    bf16x8 kf[4], qf[4], klf[4], qlf[4];
    #pragma unroll
    for (int jt = 0; jt < 4; ++jt) {
        int j = jt * 16 + fr; if (j > 48) j = 48;
        const u16* base = qkvl + (rowb + j) * 3840;
        kf[jt] = *(const bf16x8*)(base + 1024 + h * 32 + fq * 8);
        klf[jt] = zero8();
        if (fq == 0) klf[jt] = *(const bf16x8*)(base + 3328 + h * 8);
    }
    #pragma unroll
    for (int it = 0; it < 4; ++it) {
        int i = it * 16 + fr; if (i > 48) i = 48;
        const u16* base = qkvl + (rowb + i) * 3840;
        qf[it] = *(const bf16x8*)(base + h * 32 + fq * 8);
        qlf[it] = zero8();
        if (fq == 0) qlf[it] = *(const bf16x8*)(base + 3072 + h * 8);
    }

    // ---- S^T = K·Q : D[row=j][col=i] ----
    f32x4 sT[4][4], sl[4][4];
    #pragma unroll
    for (int jt = 0; jt < 4; ++jt)
        #pragma unroll
        for (int it = 0; it < 4; ++it) {
            sT[jt][it] = (f32x4){0.f, 0.f, 0.f, 0.f};
            sl[jt][it] = (f32x4){0.f, 0.f, 0.f, 0.f};
        }
    #pragma unroll
    for (int jt = 0; jt < 4; ++jt)
        #pragma unroll
        for (int it = 0; it < 4; ++it)
            sT[jt][it] = __builtin_amdgcn_mfma_f32_16x16x32_bf16(kf[jt], qf[it], sT[jt][it], 0, 0, 0);
    #pragma unroll
    for (int jt = 0; jt < 4; ++jt)
        #pragma unroll
        for (int it = 0; it < 4; ++it)
            sl[jt][it] = __builtin_amdgcn_mfma_f32_16x16x32_bf16(klf[jt], qlf[it], sl[jt][it], 0, 0, 0);

    __syncthreads();   // maskb/rpi16/rpbl ready

    // ---- bias + mask (element: j = jt*16+fq*4+r, i = it*16+fr) ----
    const float scale   = 0.17677669529663687f;   // 32^-0.5
    const float scale_l = 0.35355339059327373f;   // 8^-0.5
    const int ic = (fr > 0 && (fr + 48) > 48) ? 0 : 0; (void)ic;
    #pragma unroll
    for (int it = 0; it < 4; ++it) {
        int i = it * 16 + fr;
        int icl = i < 49 ? i : 48;
        #pragma unroll
        for (int jt = 0; jt < 4; ++jt) {
            #pragma unroll
            for (int r = 0; r < 4; ++r) {
                int j = jt * 16 + fq * 4 + r;
                int jcl = j < 49 ? j : 48;
                int ij = icl * 49 + jcl;
                float bm = b2f(maskb[ij]) + rpbl[w * 169 + rpi16[ij]];
                float S  = sT[jt][it][r] * scale   + bm;
                float Sl = sl[jt][it][r] * scale_l + bm;
                if (j >= 49) { S = -1e30f; Sl = -1e30f; }
                sT[jt][it][r] = S;
                sl[jt][it][r] = Sl;
            }
        }
    }

    const float lam1 = 1.f / (1.f + __expf(-*lam1p));
    const float lam2 = 1.f / (1.f + __expf(-*lam2p));

    // ---- dual softmax over j (rows of S^T) per column i; diff into sl ----
    #pragma unroll
    for (int it = 0; it < 4; ++it) {
        float mx = -1e30f, ml = -1e30f;
        #pragma unroll
        for (int jt = 0; jt < 4; ++jt)
            #pragma unroll
            for (int r = 0; r < 4; ++r) {
                mx = fmaxf(mx, sT[jt][it][r]);
                ml = fmaxf(ml, sl[jt][it][r]);
            }
        mx = fmaxf(mx, __shfl_xor(mx, 16)); mx = fmaxf(mx, __shfl_xor(mx, 32));
        ml = fmaxf(ml, __shfl_xor(ml, 16)); ml = fmaxf(ml, __shfl_xor(ml, 32));
        float sum = 0.f, suml = 0.f;
        #pragma unroll
        for (int jt = 0; jt < 4; ++jt)
            #pragma unroll
            for (int r = 0; r < 4; ++r) {
                float e  = __expf(sT[jt][it][r] - mx);
                float el = __expf(sl[jt][it][r] - ml);
                sT[jt][it][r] = e;  sum  += e;
                sl[jt][it][r] = el; suml += el;
            }
        sum  += __shfl_xor(sum, 16);  sum  += __shfl_xor(sum, 32);
        suml += __shfl_xor(suml, 16); suml += __shfl_xor(suml, 32);
        float rs = 1.f / sum, rsl = 1.f / suml;
        #pragma unroll
        for (int jt = 0; jt < 4; ++jt)
            #pragma unroll
            for (int r = 0; r < 4; ++r) {
                float p  = sT[jt][it][r] * rs;
                float pl = sl[jt][it][r] * rsl;
                sT[jt][it][r] = p;
                sl[jt][it][r] = lam1 * pl - lam2 * p;
            }
    }

    // ---- write P (attn_sm): lane holds (j=jt*16+fq*4+r, i=it*16+fr) ----
    #pragma unroll
    for (int it = 0; it < 4; ++it) {
        int i = it * 16 + fr;
        if (i < 49) {
            #pragma unroll
            for (int jt = 0; jt < 4; ++jt) {
                ushort4 pk;
                pk.x = f2b(sT[jt][it][0]); pk.y = f2b(sT[jt][it][1]);
                pk.z = f2b(sT[jt][it][2]); pk.w = f2b(sT[jt][it][3]);
                *(ushort4*)&P[i * 72 + jt * 16 + fq * 4] = pk;
            }
        }
    }

    // ---- O = P·V : D[row=i][col=d] ----
    f32x4 o[4][2];
    #pragma unroll
    for (int it = 0; it < 4; ++it)
        #pragma unroll
        for (int nt = 0; nt < 2; ++nt)
            o[it][nt] = (f32x4){0.f, 0.f, 0.f, 0.f};
    #pragma unroll
    for (int kt = 0; kt < 2; ++kt) {
        bf16x8 pa[4], vb[2];
        #pragma unroll
        for (int it = 0; it < 4; ++it) {
            int row = it * 16 + fr; if (row > 48) row = 48;
            pa[it] = *(const bf16x8*)&P[row * 72 + kt * 32 + fq * 8];
        }
        #pragma unroll
        for (int nt = 0; nt < 2; ++nt)
            vb[nt] = *(const bf16x8*)&VT[(nt * 16 + fr) * 72 + kt * 32 + fq * 8];
        #pragma unroll
        for (int it = 0; it < 4; ++it)
            #pragma unroll
            for (int nt = 0; nt < 2; ++nt)
                o[it][nt] = __builtin_amdgcn_mfma_f32_16x16x32_bf16(pa[it], vb[nt], o[it][nt], 0, 0, 0);
    }

    // ---- store x_orig (fp32): row = it*16+fq*4+r, col = h*32+nt*16+fr ----
    #pragma unroll
    for (int it = 0; it < 4; ++it)
        #pragma unroll
        for (int r = 0; r < 4; ++r) {
            int i = it * 16 + fq * 4 + r;
            if (i < 49) {
                #pragma unroll
                for (int nt = 0; nt < 2; ++nt)
                    xorig_out[((size_t)b * 49 + i) * 1024 + h * 32 + nt * 16 + fr] = o[it][nt][r];
            }
        }

    // ---- write diff over P, then delta_v = diff·Vl ----
    #pragma unroll
    for (int it = 0; it < 4; ++it) {
        int i = it * 16 + fr;
        if (i < 49) {
            #pragma unroll
            for (int jt = 0; jt < 4; ++jt) {
                ushort4 pk;
                pk.x = f2b(sl[jt][it][0]); pk.y = f2b(sl[jt][it][1]);
                pk.z = f2b(sl[jt][it][2]); pk.w = f2b(sl[jt][it][3]);
                *(ushort4*)&P[i * 72 + jt * 16 + fq * 4] = pk;
            }
        }
    }
    f32x4 ol[4];
    #pragma unroll
    for (int it = 0; it < 4; ++it) ol[it] = (f32x4){0.f, 0.f, 0.f, 0.f};
    {
        int dcl = fr < 8 ? fr : 7;
        #pragma unroll
        for (int kt = 0; kt < 2; ++kt) {
            bf16x8 pa[4];
            #pragma unroll
            for (int it = 0; it < 4; ++it) {
                int row = it * 16 + fr; if (row > 48) row = 48;
                pa[it] = *(const bf16x8*)&P[row * 72 + kt * 32 + fq * 8];
            }
            bf16x8 vlb = *(const bf16x8*)&VlT[dcl * 72 + kt * 32 + fq * 8];
            #pragma unroll
            for (int it = 0; it < 4; ++it)
                ol[it] = __builtin_amdgcn_mfma_f32_16x16x32_bf16(pa[it], vlb, ol[it], 0, 0, 0);
        }
    }
    #pragma unroll
    for (int it = 0; it < 4; ++it)
        #pragma unroll
        for (int r = 0; r < 4; ++r) {
            int i = it * 16 + fq * 4 + r;
            if (i < 49 && fr < 8)
                dv_out[((size_t)b * 49 + i) * 256 + h * 8 + fr] = f2b(ol[it][r]);
        }
}

// ---------------------------------------------------------------------------
extern "C" void kernel_launch(void* const* d_in, const int* in_sizes, int n_in,
                              void* d_out, int out_size, void* d_ws, size_t ws_size,
                              hipStream_t stream)
{
    const float* x      = (const float*)d_in[0];
    const float* mask   = (const float*)d_in[1];
    const float* qkv_w  = (const float*)d_in[2];
    const float* qkv_b  = (const float*)d_in[3];
    const float* proj_w = (const float*)d_in[4];
    const float* proj_b = (const float*)d_in[5];
    const float* rpb    = (const float*)d_in[6];
    const float* ql_w   = (const float*)d_in[7];
    const float* kl_w   = (const float*)d_in[8];
    const float* vl_w   = (const float*)d_in[9];
    const float* lam1   = (const float*)d_in[10];
    const float* lam2   = (const float*)d_in[11];
    const float* dp_w   = (const float*)d_in[12];
    const float* dp_b   = (const float*)d_in[13];
    const float* gamma  = (const float*)d_in[14];
    const int*   rpi    = (const int*)d_in[15];
    float* out = (float*)d_out;

    // chunk count over windows (graph-safe: depends only on ws_size)
    int nc;
    if      (ws_size >= 267386880ull) nc = 1;
    else if (ws_size >= 145358848ull) nc = 2;
    else                              nc = 4;   // needs 84,344,832 B
    const int wpc = 512 / nc;        // windows per chunk
    const int mc  = 25088 / nc;      // token rows per chunk (multiple of 128)

    // ws layout (bf16 elements)
    u16* dv   = (u16*)d_ws;                 // 25088*256
    u16* wbuf = dv + 6422528;               // 5,242,880 elements
    u16* xbuf = wbuf + 5242880;             // mc*1024
    u16* regA = xbuf + (size_t)mc * 1024;   // mc*3840 (phase1) / mc*1024 (phase2)

    u16* w_qkv = wbuf;
    u16* w_ql  = wbuf + 3145728;
    u16* w_kl  = wbuf + 3407872;
    u16* w_vl  = wbuf + 3670016;
    u16* w_dp  = wbuf + 3932160;
    u16* w_pj  = wbuf + 4194304;

    // convert weights to bf16 (once per call)
    cvt_f32_bf16<<<3072, 256, 0, stream>>>(qkv_w,  w_qkv, 786432);
    cvt_f32_bf16<<< 256, 256, 0, stream>>>(ql_w,   w_ql,   65536);
    cvt_f32_bf16<<< 256, 256, 0, stream>>>(kl_w,   w_kl,   65536);
    cvt_f32_bf16<<< 256, 256, 0, stream>>>(vl_w,   w_vl,   65536);
    cvt_f32_bf16<<< 256, 256, 0, stream>>>(dp_w,   w_dp,   65536);
    cvt_f32_bf16<<<1024, 256, 0, stream>>>(proj_w, w_pj,  262144);

    // Phase 1: per chunk: cvt x -> qkvl GEMM -> attention
    for (int c = 0; c < nc; ++c) {
        const float* xc = x + (size_t)c * mc * 1024;
        cvt_f32_bf16<<<mc, 256, 0, stream>>>(xc, xbuf, mc * 256);
        gemm_bt<0><<<dim3(mc / 128, 30), 256, 0, stream>>>(
            xbuf, 1024, w_qkv, w_ql, w_kl, w_vl, qkv_b,
            nullptr, nullptr, regA, nullptr, 3840);
        attn_mfma<<<dim3(wpc, 8), 256, 0, stream>>>(
            regA, mask, rpb, rpi, lam1, lam2, c * wpc, out, dv);
    }
    // Phase 2: per chunk: diffproj (+residual from out scratch) -> final proj
    for (int c = 0; c < nc; ++c) {
        size_t r0 = (size_t)c * mc;
        gemm_bt<1><<<dim3(mc / 128, 8), 256, 0, stream>>>(
            dv + r0 * 256, 256, w_dp, nullptr, nullptr, nullptr, dp_b,
            out + r0 * 1024, gamma, regA, nullptr, 1024);
        gemm_bt<2><<<dim3(mc / 128, 8), 256, 0, stream>>>(
            regA, 1024, w_pj, nullptr, nullptr, nullptr, proj_b,
            nullptr, nullptr, nullptr, out + r0 * 1024, 1024);
    }
}